// Round 10
// baseline (81.895 us; speedup 1.0000x reference)
//
#include <hip/hip_runtime.h>
#include <cstdint>
#include <cstddef>

typedef __bf16 bf16x8 __attribute__((ext_vector_type(8)));
typedef float f32x4 __attribute__((ext_vector_type(4)));
typedef float f32x16 __attribute__((ext_vector_type(16)));
typedef short s16x8 __attribute__((ext_vector_type(8)));
typedef unsigned short u16x4 __attribute__((ext_vector_type(4)));
typedef unsigned short u16x8 __attribute__((ext_vector_type(8)));
typedef int i32x4 __attribute__((ext_vector_type(4)));

#define S_LEN 2048
#define DH    64
#define BK    64
#define NTILE (S_LEN / BK)
#define NH    32

#if __has_builtin(__builtin_amdgcn_exp2f)
#define EXPF(x) __builtin_amdgcn_exp2f(x)
#define QSCALE 0.18033688011112043f   /* 0.125 * log2(e) */
#else
#define EXPF(x) __expf(x)
#define QSCALE 0.125f
#endif

typedef const __attribute__((address_space(1))) void* gas_ptr;
typedef __attribute__((address_space(3))) void* las_ptr;

static __device__ __forceinline__ unsigned short f2bf(float x) {
    unsigned int u = __builtin_bit_cast(unsigned int, x);
    u += 0x7FFFu + ((u >> 16) & 1u);   // RNE
    return (unsigned short)(u >> 16);
}

static __device__ __forceinline__ unsigned cvtpk(float lo, float hi) {
    unsigned r;
    asm("v_cvt_pk_bf16_f32 %0, %1, %2" : "=v"(r) : "v"(lo), "v"(hi));
    return r;
}

// v_permlane32_swap direction (b): upper half of x <-> lower half of y.
static __device__ __forceinline__ void swap32(int& x, int& y, int hi) {
#if __has_builtin(__builtin_amdgcn_permlane32_swap)
    (void)hi;
    auto r = __builtin_amdgcn_permlane32_swap(x, y, false, false);
    x = r[0]; y = r[1];
#else
    int px = __shfl_xor(x, 32), py = __shfl_xor(y, 32);
    int nx = hi ? py : x;
    int ny = hi ? y  : px;
    x = nx; y = ny;
#endif
}

static __device__ __forceinline__ bf16x8 mkfrag(int lo0, int lo1, int up0, int up1, int hi) {
    swap32(lo0, up0, hi);
    swap32(lo1, up1, hi);
    i32x4 f = {lo0, lo1, up0, up1};
    return __builtin_bit_cast(bf16x8, f);
}

// =====================================================================
// Pre-pass (K/V only): FRAGMENT-ORDERED bf16 chunks.
//   Kf chunk id: (t*8 + dsub*2 + half)*64 + ln
//   Vf chunk id: (t*8 + ks*2   + half)*64 + ln   (V transposed)
// =====================================================================
__global__ __launch_bounds__(256) void prepass_kv(
        const float* __restrict__ K, const float* __restrict__ V,
        unsigned short* __restrict__ Kf, unsigned short* __restrict__ Vf)
{
    __shared__ float Tl[64][68];
    const int tid = threadIdx.x;
    const int head = blockIdx.x >> 5;
    const int tile = blockIdx.x & 31;

    const size_t hoff = (size_t)head * S_LEN * DH;
    const size_t soff = hoff + (size_t)tile * 64 * DH;

    // ---------- K ----------
    #pragma unroll
    for (int p = 0; p < 4; ++p) {
        const int idx = p * 256 + tid;
        const int row = idx >> 4, c4 = idx & 15;
        *(float4*)&Tl[row][c4 * 4] = *(const float4*)(K + soff + (size_t)row * DH + c4 * 4);
    }
    __syncthreads();
    #pragma unroll
    for (int p = 0; p < 2; ++p) {
        const int cid = p * 256 + tid;
        const int sub = cid >> 6;
        const int ln  = cid & 63;
        const int dsub = sub >> 1, half = sub & 1;
        const int row  = half * 32 + (ln & 31);
        const int d0   = dsub * 16 + (ln >> 5) * 8;
        u16x8 o;
        #pragma unroll
        for (int e = 0; e < 8; ++e) o[e] = f2bf(Tl[row][d0 + e]);
        *(u16x8*)&Kf[hoff + (((size_t)tile * 8 + sub) * 64 + ln) * 8] = o;
    }
    __syncthreads();

    // ---------- V (transposed into fragments) ----------
    #pragma unroll
    for (int p = 0; p < 4; ++p) {
        const int idx = p * 256 + tid;
        const int row = idx >> 4, c4 = idx & 15;
        *(float4*)&Tl[row][c4 * 4] = *(const float4*)(V + soff + (size_t)row * DH + c4 * 4);
    }
    __syncthreads();
    #pragma unroll
    for (int p = 0; p < 2; ++p) {
        const int cid = p * 256 + tid;
        const int sub = cid >> 6;
        const int ln  = cid & 63;
        const int ks = sub >> 1, half = sub & 1;
        const int k0 = ks * 16 + (ln >> 5) * 8;
        const int d  = half * 32 + (ln & 31);
        u16x8 o;
        #pragma unroll
        for (int e = 0; e < 8; ++e) o[e] = f2bf(Tl[k0 + e][d]);
        *(u16x8*)&Vf[hoff + (((size_t)tile * 8 + sub) * 64 + ln) * 8] = o;
    }
}

// =====================================================================
// Main: fused split-K, K staged in LDS (DMA), V read DIRECTLY from L2
// as per-lane fragment loads (halves the LDS pipe - it was the widest).
// 8 waves = 2 groups x 4; group g = key-half g over the same 128 q-rows.
// =====================================================================
__global__ __launch_bounds__(512, 4) void sdpa_fused(
        const float* __restrict__ Qg, const unsigned short* __restrict__ Kf,
        const unsigned short* __restrict__ Vf, float* __restrict__ O)
{
    // 36 KB: K tiles [grp][buf] at grp*8192 + buf*4096 (ushort idx) = 32 KB;
    // epilogue reuses the whole array as float[9216] (needs 8704).
    __shared__ __attribute__((aligned(16))) unsigned short SH[18432];

    const int tid = threadIdx.x;
    const int w8  = tid >> 6;        // 0..7
    const int grp = w8 >> 2;         // key-half
    const int w   = w8 & 3;          // wave within group
    const int ln  = tid & 63;
    const int r31 = ln & 31;
    const int hi  = ln >> 5;

    // XCD swizzle (bijective: 512 % 8 == 0)
    const int b2 = (blockIdx.x & 7) * 64 + (blockIdx.x >> 3);
    const int n  = b2 >> 4;
    const int qt = b2 & 15;
    const int q0 = qt * 128 + w * 32;

    const size_t hoff = (size_t)n * S_LEN * DH;
    const unsigned short* __restrict__ Kh = Kf + hoff;
    const unsigned short* __restrict__ Vh = Vf + hoff;

    const int kbase = grp * 8192;    // ushort index of this group's K tiles

    // Q fragments: fp32 direct load + scale + bf16.
    s16x8 qf[4];
    {
        const float* Qr = Qg + hoff + (size_t)(q0 + r31) * DH;
        #pragma unroll
        for (int dsub = 0; dsub < 4; ++dsub) {
            const float* s = Qr + dsub * 16 + hi * 8;
            float4 a0 = *(const float4*)s, a1 = *(const float4*)(s + 4);
            s16x8 v;
            v[0] = (short)f2bf(a0.x * QSCALE); v[1] = (short)f2bf(a0.y * QSCALE);
            v[2] = (short)f2bf(a0.z * QSCALE); v[3] = (short)f2bf(a0.w * QSCALE);
            v[4] = (short)f2bf(a1.x * QSCALE); v[5] = (short)f2bf(a1.y * QSCALE);
            v[6] = (short)f2bf(a1.z * QSCALE); v[7] = (short)f2bf(a1.w * QSCALE);
            qf[dsub] = v;
        }
    }

    float l = 0.f;
    f32x16 oacc0 = {}, oacc1 = {};

    // stage one K tile for THIS group (4 waves, 512 x 16B chunks)
    auto stage = [&](int buf, int t) {
        #pragma unroll
        for (int pass = 0; pass < 2; ++pass) {
            const int c = pass * 256 + w * 64;
            const unsigned short* gk = Kh + ((size_t)t * 512 + c + ln) * 8;
            __builtin_amdgcn_global_load_lds((gas_ptr)gk,
                    (las_ptr)&SH[kbase + buf * 4096 + c * 8], 16, 0, 0);
        }
    };

    const int t0 = grp * (NTILE / 2);   // this group's 16 tiles

    stage(0, t0);
    __syncthreads();

    auto body = [&](int it, int cur) {
        if (it + 1 < NTILE / 2) stage(cur ^ 1, t0 + it + 1);

        // ---- S^T = K Q^T (K from LDS)
        f32x16 s0 = {}, s1 = {};
        __builtin_amdgcn_s_setprio(1);
        #pragma unroll
        for (int dsub = 0; dsub < 4; ++dsub) {
            s16x8 kf0 = *(const s16x8*)&SH[kbase + cur * 4096 + ((dsub * 2 + 0) * 64 + ln) * 8];
            s16x8 kf1 = *(const s16x8*)&SH[kbase + cur * 4096 + ((dsub * 2 + 1) * 64 + ln) * 8];
            s0 = __builtin_amdgcn_mfma_f32_32x32x16_bf16(
                    __builtin_bit_cast(bf16x8, kf0),
                    __builtin_bit_cast(bf16x8, qf[dsub]), s0, 0, 0, 0);
            s1 = __builtin_amdgcn_mfma_f32_32x32x16_bf16(
                    __builtin_bit_cast(bf16x8, kf1),
                    __builtin_bit_cast(bf16x8, qf[dsub]), s1, 0, 0, 0);
        }
        __builtin_amdgcn_s_setprio(0);

        // ---- V fragments direct from L2 (fragment-ordered, coalesced);
        //      latency hidden under the softmax VALU below.
        s16x8 vfr[8];
        #pragma unroll
        for (int u = 0; u < 8; ++u)
            vfr[u] = *(const s16x8*)(Vh + (((size_t)(t0 + it) * 8 + u) * 64 + ln) * 8);

        // ---- zero-max softmax, in place
        #pragma unroll
        for (int i = 0; i < 16; ++i) {
            s0[i] = EXPF(s0[i]);
            s1[i] = EXPF(s1[i]);
        }
        {
            float a0 = 0.f, a1 = 0.f, a2 = 0.f, a3 = 0.f;
            #pragma unroll
            for (int i = 0; i < 16; i += 4) {
                a0 += s0[i];     a1 += s0[i + 1];
                a2 += s0[i + 2]; a3 += s0[i + 3];
                a0 += s1[i];     a1 += s1[i + 1];
                a2 += s1[i + 2]; a3 += s1[i + 3];
            }
            l += (a0 + a1) + (a2 + a3);
        }

        // ---- P^T -> bf16 B-fragments in-register (T12)
        unsigned wa[8], wb[8];
        #pragma unroll
        for (int i = 0; i < 8; ++i) {
            wa[i] = cvtpk(s0[2 * i], s0[2 * i + 1]);
            wb[i] = cvtpk(s1[2 * i], s1[2 * i + 1]);
        }
        bf16x8 pf[4];
        pf[0] = mkfrag(wa[0], wa[1], wa[2], wa[3], hi);
        pf[1] = mkfrag(wa[4], wa[5], wa[6], wa[7], hi);
        pf[2] = mkfrag(wb[0], wb[1], wb[2], wb[3], hi);
        pf[3] = mkfrag(wb[4], wb[5], wb[6], wb[7], hi);

        // ---- O^T += V^T P^T (V from registers)
        __builtin_amdgcn_s_setprio(1);
        #pragma unroll
        for (int ks = 0; ks < 4; ++ks) {
            oacc0 = __builtin_amdgcn_mfma_f32_32x32x16_bf16(
                    __builtin_bit_cast(bf16x8, vfr[ks * 2 + 0]), pf[ks], oacc0, 0, 0, 0);
            oacc1 = __builtin_amdgcn_mfma_f32_32x32x16_bf16(
                    __builtin_bit_cast(bf16x8, vfr[ks * 2 + 1]), pf[ks], oacc1, 0, 0, 0);
        }
        __builtin_amdgcn_s_setprio(0);

        __syncthreads();
    };

    for (int it = 0; it < NTILE / 2; it += 2) {
        body(it, 0);
        body(it + 1, 1);
    }

    // ---- fused combine: group 1 -> LDS, group 0 adds + normalizes + stores
    const float lt = l + __shfl_xor(l, 32);   // this group's full denominator

    float* xch = (float*)SH;                   // safe: all past final barrier
    if (grp == 1) {
        float* dst = xch + ((size_t)(w * 64 + ln)) * 34;
        #pragma unroll
        for (int i = 0; i < 16; ++i) {
            dst[i]      = oacc0[i];
            dst[16 + i] = oacc1[i];
        }
        dst[32] = lt;
    }
    __syncthreads();
    if (grp == 0) {
        const float* src = xch + ((size_t)(w * 64 + ln)) * 34;
        const float inv = 1.0f / (lt + src[32]);
        float* Orow = O + hoff + (size_t)(q0 + r31) * DH;
        #pragma unroll
        for (int g = 0; g < 4; ++g) {
            float4 o0 = { (oacc0[4*g]   + src[4*g])     * inv,
                          (oacc0[4*g+1] + src[4*g+1])   * inv,
                          (oacc0[4*g+2] + src[4*g+2])   * inv,
                          (oacc0[4*g+3] + src[4*g+3])   * inv };
            *(float4*)&Orow[g * 8 + hi * 4] = o0;
            float4 o1 = { (oacc1[4*g]   + src[16+4*g])   * inv,
                          (oacc1[4*g+1] + src[16+4*g+1]) * inv,
                          (oacc1[4*g+2] + src[16+4*g+2]) * inv,
                          (oacc1[4*g+3] + src[16+4*g+3]) * inv };
            *(float4*)&Orow[32 + g * 8 + hi * 4] = o1;
        }
    }
}

// ---------------- fallback (fp32 in, self-staging, round-1 proven) ------
static __device__ __forceinline__ int swz_fb(int row, int col) {
    return row * 64 + (col ^ ((row & 7) << 3));
}

__global__ __launch_bounds__(256) void sdpa_fwd_fb(
        const float* __restrict__ Q, const float* __restrict__ K,
        const float* __restrict__ V, float* __restrict__ O)
{
    __shared__ __attribute__((aligned(16))) unsigned short Klf[BK * DH];
    __shared__ __attribute__((aligned(16))) unsigned short Vtf[DH * BK];
    __shared__ __attribute__((aligned(16))) unsigned short Plf[4][16 * BK];

    const int tid = threadIdx.x;
    const int w = tid >> 6, ln = tid & 63, lg = ln >> 4, lr = ln & 15;
    const int n = blockIdx.x >> 5, qt = blockIdx.x & 31;
    const int q0 = qt * 64 + w * 16;
    const size_t hoff = (size_t)n * S_LEN * DH;
    const float *Qh = Q + hoff, *Kh = K + hoff, *Vh = V + hoff;
    float* Oh = O + hoff;

    s16x8 qf[2];
    #pragma unroll
    for (int t = 0; t < 2; ++t) {
        const float* src = Qh + (size_t)(q0 + lr) * DH + t * 32 + lg * 8;
        float4 a = *(const float4*)(src);
        float4 b = *(const float4*)(src + 4);
        s16x8 v;
        v[0] = (short)f2bf(a.x * 0.125f); v[1] = (short)f2bf(a.y * 0.125f);
        v[2] = (short)f2bf(a.z * 0.125f); v[3] = (short)f2bf(a.w * 0.125f);
        v[4] = (short)f2bf(b.x * 0.125f); v[5] = (short)f2bf(b.y * 0.125f);
        v[6] = (short)f2bf(b.z * 0.125f); v[7] = (short)f2bf(b.w * 0.125f);
        qf[t] = v;
    }
    float mrow[4] = {-INFINITY, -INFINITY, -INFINITY, -INFINITY};
    float lrow[4] = {0.f, 0.f, 0.f, 0.f};
    f32x4 oacc[4];
    #pragma unroll
    for (int nn = 0; nn < 4; ++nn) oacc[nn] = (f32x4){0.f, 0.f, 0.f, 0.f};

    for (int it = 0; it < NTILE; ++it) {
        const int k0 = it * BK;
        __syncthreads();
        #pragma unroll
        for (int r4 = 0; r4 < 4; ++r4) {
            const int lin = tid + 256 * r4;
            const int row = lin >> 4, c4 = lin & 15;
            float4 kv = *(const float4*)(Kh + (size_t)(k0 + row) * DH + c4 * 4);
            u16x4 kb;
            kb[0] = f2bf(kv.x); kb[1] = f2bf(kv.y); kb[2] = f2bf(kv.z); kb[3] = f2bf(kv.w);
            *(u16x4*)&Klf[swz_fb(row, c4 * 4)] = kb;
            float4 vv = *(const float4*)(Vh + (size_t)(k0 + row) * DH + c4 * 4);
            const float vals[4] = {vv.x, vv.y, vv.z, vv.w};
            #pragma unroll
            for (int ii = 0; ii < 4; ++ii) Vtf[swz_fb(c4 * 4 + ii, row)] = f2bf(vals[ii]);
        }
        __syncthreads();
        f32x4 sacc[4];
        #pragma unroll
        for (int kt = 0; kt < 4; ++kt) {
            f32x4 acc = (f32x4){0.f, 0.f, 0.f, 0.f};
            #pragma unroll
            for (int t = 0; t < 2; ++t) {
                s16x8 kf = *(const s16x8*)&Klf[swz_fb(kt * 16 + lr, t * 32 + lg * 8)];
                acc = __builtin_amdgcn_mfma_f32_16x16x32_bf16(
                        __builtin_bit_cast(bf16x8, qf[t]),
                        __builtin_bit_cast(bf16x8, kf), acc, 0, 0, 0);
            }
            sacc[kt] = acc;
        }
        float alpha[4];
        #pragma unroll
        for (int j = 0; j < 4; ++j) {
            float v = fmaxf(fmaxf(sacc[0][j], sacc[1][j]), fmaxf(sacc[2][j], sacc[3][j]));
            #pragma unroll
            for (int off = 1; off < 16; off <<= 1) v = fmaxf(v, __shfl_xor(v, off));
            const float mn = fmaxf(mrow[j], v);
            alpha[j] = __expf(mrow[j] - mn);
            mrow[j] = mn;
        }
        float psum[4] = {0.f, 0.f, 0.f, 0.f};
        #pragma unroll
        for (int kt = 0; kt < 4; ++kt) {
            #pragma unroll
            for (int j = 0; j < 4; ++j) {
                const float p = __expf(sacc[kt][j] - mrow[j]);
                const unsigned short pb = f2bf(p);
                unsigned int pu = ((unsigned int)pb) << 16;
                psum[j] += __builtin_bit_cast(float, pu);
                Plf[w][swz_fb(lg * 4 + j, kt * 16 + lr)] = pb;
            }
        }
        #pragma unroll
        for (int j = 0; j < 4; ++j) {
            float s = psum[j];
            #pragma unroll
            for (int off = 1; off < 16; off <<= 1) s += __shfl_xor(s, off);
            lrow[j] = lrow[j] * alpha[j] + s;
        }
        #pragma unroll
        for (int nn = 0; nn < 4; ++nn) {
            #pragma unroll
            for (int j = 0; j < 4; ++j) oacc[nn][j] *= alpha[j];
        }
        #pragma unroll
        for (int t = 0; t < 2; ++t) {
            s16x8 pf = *(const s16x8*)&Plf[w][swz_fb(lr, t * 32 + lg * 8)];
            #pragma unroll
            for (int nn = 0; nn < 4; ++nn) {
                s16x8 vf = *(const s16x8*)&Vtf[swz_fb(nn * 16 + lr, t * 32 + lg * 8)];
                oacc[nn] = __builtin_amdgcn_mfma_f32_16x16x32_bf16(
                        __builtin_bit_cast(bf16x8, pf),
                        __builtin_bit_cast(bf16x8, vf), oacc[nn], 0, 0, 0);
            }
        }
    }
    #pragma unroll
    for (int j = 0; j < 4; ++j) {
        const float inv = 1.0f / lrow[j];
        #pragma unroll
        for (int nn = 0; nn < 4; ++nn)
            Oh[(size_t)(q0 + lg * 4 + j) * DH + nn * 16 + lr] = oacc[nn][j] * inv;
    }
}

extern "C" void kernel_launch(void* const* d_in, const int* in_sizes, int n_in,
                              void* d_out, int out_size, void* d_ws, size_t ws_size,
                              hipStream_t stream) {
    const float* Q = (const float*)d_in[0];
    const float* K = (const float*)d_in[1];
    const float* V = (const float*)d_in[2];
    float* O = (float*)d_out;

    const size_t elems    = (size_t)NH * S_LEN * DH;   // 4.19M
    const size_t bf_bytes = elems * 2;                 // 8MB per tensor

    unsigned short* Kf = (unsigned short*)d_ws;
    unsigned short* Vf = Kf + elems;

    if (ws_size >= 2 * bf_bytes) {
        prepass_kv<<<NH * 32, 256, 0, stream>>>(K, V, Kf, Vf);
        sdpa_fused<<<NH * 16, 512, 0, stream>>>(Q, Kf, Vf, O);
    } else {
        sdpa_fwd_fb<<<NH * (S_LEN / 64), 256, 0, stream>>>(Q, K, V, O);
    }
}

// Round 11
// 58.393 us; speedup vs baseline: 1.4025x; 1.4025x over previous
//
#include <hip/hip_runtime.h>
#include <cstdint>
#include <cstddef>

typedef __bf16 bf16x8 __attribute__((ext_vector_type(8)));
typedef float f32x4 __attribute__((ext_vector_type(4)));
typedef float f32x16 __attribute__((ext_vector_type(16)));
typedef short s16x8 __attribute__((ext_vector_type(8)));
typedef unsigned short u16x4 __attribute__((ext_vector_type(4)));
typedef unsigned short u16x8 __attribute__((ext_vector_type(8)));
typedef int i32x4 __attribute__((ext_vector_type(4)));

#define S_LEN 2048
#define DH    64
#define BK    64
#define NTILE (S_LEN / BK)
#define NH    32

#if __has_builtin(__builtin_amdgcn_exp2f)
#define EXPF(x) __builtin_amdgcn_exp2f(x)
#define QSCALE 0.18033688011112043f   /* 0.125 * log2(e) */
#else
#define EXPF(x) __expf(x)
#define QSCALE 0.125f
#endif

typedef const __attribute__((address_space(1))) void* gas_ptr;
typedef __attribute__((address_space(3))) void* las_ptr;

static __device__ __forceinline__ unsigned short f2bf(float x) {
    unsigned int u = __builtin_bit_cast(unsigned int, x);
    u += 0x7FFFu + ((u >> 16) & 1u);   // RNE
    return (unsigned short)(u >> 16);
}

static __device__ __forceinline__ unsigned cvtpk(float lo, float hi) {
    unsigned r;
    asm("v_cvt_pk_bf16_f32 %0, %1, %2" : "=v"(r) : "v"(lo), "v"(hi));
    return r;
}

// v_permlane32_swap direction (b): upper half of x <-> lower half of y.
static __device__ __forceinline__ void swap32(int& x, int& y, int hi) {
#if __has_builtin(__builtin_amdgcn_permlane32_swap)
    (void)hi;
    auto r = __builtin_amdgcn_permlane32_swap(x, y, false, false);
    x = r[0]; y = r[1];
#else
    int px = __shfl_xor(x, 32), py = __shfl_xor(y, 32);
    int nx = hi ? py : x;
    int ny = hi ? y  : px;
    x = nx; y = ny;
#endif
}

static __device__ __forceinline__ bf16x8 mkfrag(int lo0, int lo1, int up0, int up1, int hi) {
    swap32(lo0, up0, hi);
    swap32(lo1, up1, hi);
    i32x4 f = {lo0, lo1, up0, up1};
    return __builtin_bit_cast(bf16x8, f);
}

// =====================================================================
// Pre-pass (K/V only): FRAGMENT-ORDERED bf16 chunks (round-8-proven).
//   Kf chunk id: (t*8 + dsub*2 + half)*64 + ln
//   Vf chunk id: (t*8 + ks*2   + half)*64 + ln   (V transposed)
// =====================================================================
__global__ __launch_bounds__(256) void prepass_kv(
        const float* __restrict__ K, const float* __restrict__ V,
        unsigned short* __restrict__ Kf, unsigned short* __restrict__ Vf)
{
    __shared__ float Tl[64][68];
    const int tid = threadIdx.x;
    const int head = blockIdx.x >> 5;
    const int tile = blockIdx.x & 31;

    const size_t hoff = (size_t)head * S_LEN * DH;
    const size_t soff = hoff + (size_t)tile * 64 * DH;

    // ---------- K ----------
    #pragma unroll
    for (int p = 0; p < 4; ++p) {
        const int idx = p * 256 + tid;
        const int row = idx >> 4, c4 = idx & 15;
        *(float4*)&Tl[row][c4 * 4] = *(const float4*)(K + soff + (size_t)row * DH + c4 * 4);
    }
    __syncthreads();
    #pragma unroll
    for (int p = 0; p < 2; ++p) {
        const int cid = p * 256 + tid;
        const int sub = cid >> 6;
        const int ln  = cid & 63;
        const int dsub = sub >> 1, half = sub & 1;
        const int row  = half * 32 + (ln & 31);
        const int d0   = dsub * 16 + (ln >> 5) * 8;
        u16x8 o;
        #pragma unroll
        for (int e = 0; e < 8; ++e) o[e] = f2bf(Tl[row][d0 + e]);
        *(u16x8*)&Kf[hoff + (((size_t)tile * 8 + sub) * 64 + ln) * 8] = o;
    }
    __syncthreads();

    // ---------- V (transposed into fragments) ----------
    #pragma unroll
    for (int p = 0; p < 4; ++p) {
        const int idx = p * 256 + tid;
        const int row = idx >> 4, c4 = idx & 15;
        *(float4*)&Tl[row][c4 * 4] = *(const float4*)(V + soff + (size_t)row * DH + c4 * 4);
    }
    __syncthreads();
    #pragma unroll
    for (int p = 0; p < 2; ++p) {
        const int cid = p * 256 + tid;
        const int sub = cid >> 6;
        const int ln  = cid & 63;
        const int ks = sub >> 1, half = sub & 1;
        const int k0 = ks * 16 + (ln >> 5) * 8;
        const int d  = half * 32 + (ln & 31);
        u16x8 o;
        #pragma unroll
        for (int e = 0; e < 8; ++e) o[e] = f2bf(Tl[k0 + e][d]);
        *(u16x8*)&Vf[hoff + (((size_t)tile * 8 + sub) * 64 + ln) * 8] = o;
    }
}

// =====================================================================
// Main: fused split-K (round-9 structure, K AND V staged in LDS via DMA).
// Body interleaves softmax-VALU of subtile 1 with PV-MFMA of subtile 0.
// 8 waves = 2 groups x 4; group g = key-half g over the same 128 q-rows.
// =====================================================================
__global__ __launch_bounds__(512, 4) void sdpa_fused(
        const float* __restrict__ Qg, const unsigned short* __restrict__ Kf,
        const unsigned short* __restrict__ Vf, float* __restrict__ O)
{
    // 64KB: K tiles [grp][buf] at grp*8192+buf*4096 (ushort idx), V at
    // 16384 + grp*8192 + buf*4096. Epilogue reuses as float[] (needs 34.8KB).
    __shared__ __attribute__((aligned(16))) unsigned short SH[32768];

    const int tid = threadIdx.x;
    const int w8  = tid >> 6;        // 0..7
    const int grp = w8 >> 2;         // key-half
    const int w   = w8 & 3;          // wave within group
    const int ln  = tid & 63;
    const int r31 = ln & 31;
    const int hi  = ln >> 5;

    // XCD swizzle (bijective: 512 % 8 == 0)
    const int b2 = (blockIdx.x & 7) * 64 + (blockIdx.x >> 3);
    const int n  = b2 >> 4;
    const int qt = b2 & 15;
    const int q0 = qt * 128 + w * 32;

    const size_t hoff = (size_t)n * S_LEN * DH;
    const unsigned short* __restrict__ Kh = Kf + hoff;
    const unsigned short* __restrict__ Vh = Vf + hoff;

    const int kbase = grp * 8192;            // ushort index of this group's K
    const int vbase = 16384 + grp * 8192;    // this group's V

    // Q fragments: fp32 direct load + scale + bf16.
    s16x8 qf[4];
    {
        const float* Qr = Qg + hoff + (size_t)(q0 + r31) * DH;
        #pragma unroll
        for (int dsub = 0; dsub < 4; ++dsub) {
            const float* s = Qr + dsub * 16 + hi * 8;
            float4 a0 = *(const float4*)s, a1 = *(const float4*)(s + 4);
            s16x8 v;
            v[0] = (short)f2bf(a0.x * QSCALE); v[1] = (short)f2bf(a0.y * QSCALE);
            v[2] = (short)f2bf(a0.z * QSCALE); v[3] = (short)f2bf(a0.w * QSCALE);
            v[4] = (short)f2bf(a1.x * QSCALE); v[5] = (short)f2bf(a1.y * QSCALE);
            v[6] = (short)f2bf(a1.z * QSCALE); v[7] = (short)f2bf(a1.w * QSCALE);
            qf[dsub] = v;
        }
    }

    float l = 0.f;
    f32x16 oacc0 = {}, oacc1 = {};

    // stage one K/V tile for THIS group (4 waves, 512 chunks of 16B each)
    auto stage = [&](int buf, int t) {
        #pragma unroll
        for (int pass = 0; pass < 2; ++pass) {
            const int c = pass * 256 + w * 64;
            const unsigned short* gk = Kh + ((size_t)t * 512 + c + ln) * 8;
            __builtin_amdgcn_global_load_lds((gas_ptr)gk,
                    (las_ptr)&SH[kbase + buf * 4096 + c * 8], 16, 0, 0);
            const unsigned short* gv = Vh + ((size_t)t * 512 + c + ln) * 8;
            __builtin_amdgcn_global_load_lds((gas_ptr)gv,
                    (las_ptr)&SH[vbase + buf * 4096 + c * 8], 16, 0, 0);
        }
    };

    const int t0 = grp * (NTILE / 2);   // this group's 16 tiles

    stage(0, t0);
    __syncthreads();

    auto body = [&](int it, int cur) {
        if (it + 1 < NTILE / 2) stage(cur ^ 1, t0 + it + 1);

        // ---- S^T = K Q^T
        f32x16 s0 = {}, s1 = {};
        __builtin_amdgcn_s_setprio(1);
        #pragma unroll
        for (int dsub = 0; dsub < 4; ++dsub) {
            s16x8 kf0 = *(const s16x8*)&SH[kbase + cur * 4096 + ((dsub * 2 + 0) * 64 + ln) * 8];
            s16x8 kf1 = *(const s16x8*)&SH[kbase + cur * 4096 + ((dsub * 2 + 1) * 64 + ln) * 8];
            s0 = __builtin_amdgcn_mfma_f32_32x32x16_bf16(
                    __builtin_bit_cast(bf16x8, kf0),
                    __builtin_bit_cast(bf16x8, qf[dsub]), s0, 0, 0, 0);
            s1 = __builtin_amdgcn_mfma_f32_32x32x16_bf16(
                    __builtin_bit_cast(bf16x8, kf1),
                    __builtin_bit_cast(bf16x8, qf[dsub]), s1, 0, 0, 0);
        }
        __builtin_amdgcn_s_setprio(0);

        // ---- softmax of subtile 0 (keys 0..31), zero-max, in place
        #pragma unroll
        for (int i = 0; i < 16; ++i) s0[i] = EXPF(s0[i]);
        {
            float a0 = 0.f, a1 = 0.f, a2 = 0.f, a3 = 0.f;
            #pragma unroll
            for (int i = 0; i < 16; i += 4) {
                a0 += s0[i];     a1 += s0[i + 1];
                a2 += s0[i + 2]; a3 += s0[i + 3];
            }
            l += (a0 + a1) + (a2 + a3);
        }
        bf16x8 pf0, pf1;
        {
            unsigned wa[8];
            #pragma unroll
            for (int i = 0; i < 8; ++i) wa[i] = cvtpk(s0[2 * i], s0[2 * i + 1]);
            pf0 = mkfrag(wa[0], wa[1], wa[2], wa[3], hi);   // keys  0..15
            pf1 = mkfrag(wa[4], wa[5], wa[6], wa[7], hi);   // keys 16..31
        }

        // ---- PV first half (ks=0,1): MFMAs in flight while subtile-1
        //      softmax VALU below issues (separate pipes).
        s16x8 vf0 = *(const s16x8*)&SH[vbase + cur * 4096 + ((0 * 64 + ln)) * 8];
        s16x8 vf1 = *(const s16x8*)&SH[vbase + cur * 4096 + ((1 * 64 + ln)) * 8];
        s16x8 vf2 = *(const s16x8*)&SH[vbase + cur * 4096 + ((2 * 64 + ln)) * 8];
        s16x8 vf3 = *(const s16x8*)&SH[vbase + cur * 4096 + ((3 * 64 + ln)) * 8];
        __builtin_amdgcn_s_setprio(1);
        oacc0 = __builtin_amdgcn_mfma_f32_32x32x16_bf16(
                __builtin_bit_cast(bf16x8, vf0), pf0, oacc0, 0, 0, 0);
        oacc1 = __builtin_amdgcn_mfma_f32_32x32x16_bf16(
                __builtin_bit_cast(bf16x8, vf1), pf0, oacc1, 0, 0, 0);
        oacc0 = __builtin_amdgcn_mfma_f32_32x32x16_bf16(
                __builtin_bit_cast(bf16x8, vf2), pf1, oacc0, 0, 0, 0);
        oacc1 = __builtin_amdgcn_mfma_f32_32x32x16_bf16(
                __builtin_bit_cast(bf16x8, vf3), pf1, oacc1, 0, 0, 0);
        __builtin_amdgcn_s_setprio(0);

        // ---- softmax of subtile 1 (keys 32..63) — overlaps PV above
        #pragma unroll
        for (int i = 0; i < 16; ++i) s1[i] = EXPF(s1[i]);
        {
            float a0 = 0.f, a1 = 0.f, a2 = 0.f, a3 = 0.f;
            #pragma unroll
            for (int i = 0; i < 16; i += 4) {
                a0 += s1[i];     a1 += s1[i + 1];
                a2 += s1[i + 2]; a3 += s1[i + 3];
            }
            l += (a0 + a1) + (a2 + a3);
        }
        bf16x8 pf2, pf3;
        {
            unsigned wb[8];
            #pragma unroll
            for (int i = 0; i < 8; ++i) wb[i] = cvtpk(s1[2 * i], s1[2 * i + 1]);
            pf2 = mkfrag(wb[0], wb[1], wb[2], wb[3], hi);   // keys 32..47
            pf3 = mkfrag(wb[4], wb[5], wb[6], wb[7], hi);   // keys 48..63
        }

        // ---- PV second half (ks=2,3)
        s16x8 vf4 = *(const s16x8*)&SH[vbase + cur * 4096 + ((4 * 64 + ln)) * 8];
        s16x8 vf5 = *(const s16x8*)&SH[vbase + cur * 4096 + ((5 * 64 + ln)) * 8];
        s16x8 vf6 = *(const s16x8*)&SH[vbase + cur * 4096 + ((6 * 64 + ln)) * 8];
        s16x8 vf7 = *(const s16x8*)&SH[vbase + cur * 4096 + ((7 * 64 + ln)) * 8];
        __builtin_amdgcn_s_setprio(1);
        oacc0 = __builtin_amdgcn_mfma_f32_32x32x16_bf16(
                __builtin_bit_cast(bf16x8, vf4), pf2, oacc0, 0, 0, 0);
        oacc1 = __builtin_amdgcn_mfma_f32_32x32x16_bf16(
                __builtin_bit_cast(bf16x8, vf5), pf2, oacc1, 0, 0, 0);
        oacc0 = __builtin_amdgcn_mfma_f32_32x32x16_bf16(
                __builtin_bit_cast(bf16x8, vf6), pf3, oacc0, 0, 0, 0);
        oacc1 = __builtin_amdgcn_mfma_f32_32x32x16_bf16(
                __builtin_bit_cast(bf16x8, vf7), pf3, oacc1, 0, 0, 0);
        __builtin_amdgcn_s_setprio(0);

        __syncthreads();
    };

    for (int it = 0; it < NTILE / 2; it += 2) {
        body(it, 0);
        body(it + 1, 1);
    }

    // ---- fused combine: group 1 -> LDS, group 0 adds + normalizes + stores
    const float lt = l + __shfl_xor(l, 32);   // this group's full denominator

    float* xch = (float*)SH;                   // all waves past final barrier
    if (grp == 1) {
        float* dst = xch + ((size_t)(w * 64 + ln)) * 34;
        #pragma unroll
        for (int i = 0; i < 16; ++i) {
            dst[i]      = oacc0[i];
            dst[16 + i] = oacc1[i];
        }
        dst[32] = lt;
    }
    __syncthreads();
    if (grp == 0) {
        const float* src = xch + ((size_t)(w * 64 + ln)) * 34;
        const float inv = 1.0f / (lt + src[32]);
        float* Orow = O + hoff + (size_t)(q0 + r31) * DH;
        #pragma unroll
        for (int g = 0; g < 4; ++g) {
            float4 o0 = { (oacc0[4*g]   + src[4*g])     * inv,
                          (oacc0[4*g+1] + src[4*g+1])   * inv,
                          (oacc0[4*g+2] + src[4*g+2])   * inv,
                          (oacc0[4*g+3] + src[4*g+3])   * inv };
            *(float4*)&Orow[g * 8 + hi * 4] = o0;
            float4 o1 = { (oacc1[4*g]   + src[16+4*g])   * inv,
                          (oacc1[4*g+1] + src[16+4*g+1]) * inv,
                          (oacc1[4*g+2] + src[16+4*g+2]) * inv,
                          (oacc1[4*g+3] + src[16+4*g+3]) * inv };
            *(float4*)&Orow[32 + g * 8 + hi * 4] = o1;
        }
    }
}

// ---------------- fallback (fp32 in, self-staging, round-1 proven) ------
static __device__ __forceinline__ int swz_fb(int row, int col) {
    return row * 64 + (col ^ ((row & 7) << 3));
}

__global__ __launch_bounds__(256) void sdpa_fwd_fb(
        const float* __restrict__ Q, const float* __restrict__ K,
        const float* __restrict__ V, float* __restrict__ O)
{
    __shared__ __attribute__((aligned(16))) unsigned short Klf[BK * DH];
    __shared__ __attribute__((aligned(16))) unsigned short Vtf[DH * BK];
    __shared__ __attribute__((aligned(16))) unsigned short Plf[4][16 * BK];

    const int tid = threadIdx.x;
    const int w = tid >> 6, ln = tid & 63, lg = ln >> 4, lr = ln & 15;
    const int n = blockIdx.x >> 5, qt = blockIdx.x & 31;
    const int q0 = qt * 64 + w * 16;
    const size_t hoff = (size_t)n * S_LEN * DH;
    const float *Qh = Q + hoff, *Kh = K + hoff, *Vh = V + hoff;
    float* Oh = O + hoff;

    s16x8 qf[2];
    #pragma unroll
    for (int t = 0; t < 2; ++t) {
        const float* src = Qh + (size_t)(q0 + lr) * DH + t * 32 + lg * 8;
        float4 a = *(const float4*)(src);
        float4 b = *(const float4*)(src + 4);
        s16x8 v;
        v[0] = (short)f2bf(a.x * 0.125f); v[1] = (short)f2bf(a.y * 0.125f);
        v[2] = (short)f2bf(a.z * 0.125f); v[3] = (short)f2bf(a.w * 0.125f);
        v[4] = (short)f2bf(b.x * 0.125f); v[5] = (short)f2bf(b.y * 0.125f);
        v[6] = (short)f2bf(b.z * 0.125f); v[7] = (short)f2bf(b.w * 0.125f);
        qf[t] = v;
    }
    float mrow[4] = {-INFINITY, -INFINITY, -INFINITY, -INFINITY};
    float lrow[4] = {0.f, 0.f, 0.f, 0.f};
    f32x4 oacc[4];
    #pragma unroll
    for (int nn = 0; nn < 4; ++nn) oacc[nn] = (f32x4){0.f, 0.f, 0.f, 0.f};

    for (int it = 0; it < NTILE; ++it) {
        const int k0 = it * BK;
        __syncthreads();
        #pragma unroll
        for (int r4 = 0; r4 < 4; ++r4) {
            const int lin = tid + 256 * r4;
            const int row = lin >> 4, c4 = lin & 15;
            float4 kv = *(const float4*)(Kh + (size_t)(k0 + row) * DH + c4 * 4);
            u16x4 kb;
            kb[0] = f2bf(kv.x); kb[1] = f2bf(kv.y); kb[2] = f2bf(kv.z); kb[3] = f2bf(kv.w);
            *(u16x4*)&Klf[swz_fb(row, c4 * 4)] = kb;
            float4 vv = *(const float4*)(Vh + (size_t)(k0 + row) * DH + c4 * 4);
            const float vals[4] = {vv.x, vv.y, vv.z, vv.w};
            #pragma unroll
            for (int ii = 0; ii < 4; ++ii) Vtf[swz_fb(c4 * 4 + ii, row)] = f2bf(vals[ii]);
        }
        __syncthreads();
        f32x4 sacc[4];
        #pragma unroll
        for (int kt = 0; kt < 4; ++kt) {
            f32x4 acc = (f32x4){0.f, 0.f, 0.f, 0.f};
            #pragma unroll
            for (int t = 0; t < 2; ++t) {
                s16x8 kf = *(const s16x8*)&Klf[swz_fb(kt * 16 + lr, t * 32 + lg * 8)];
                acc = __builtin_amdgcn_mfma_f32_16x16x32_bf16(
                        __builtin_bit_cast(bf16x8, qf[t]),
                        __builtin_bit_cast(bf16x8, kf), acc, 0, 0, 0);
            }
            sacc[kt] = acc;
        }
        float alpha[4];
        #pragma unroll
        for (int j = 0; j < 4; ++j) {
            float v = fmaxf(fmaxf(sacc[0][j], sacc[1][j]), fmaxf(sacc[2][j], sacc[3][j]));
            #pragma unroll
            for (int off = 1; off < 16; off <<= 1) v = fmaxf(v, __shfl_xor(v, off));
            const float mn = fmaxf(mrow[j], v);
            alpha[j] = __expf(mrow[j] - mn);
            mrow[j] = mn;
        }
        float psum[4] = {0.f, 0.f, 0.f, 0.f};
        #pragma unroll
        for (int kt = 0; kt < 4; ++kt) {
            #pragma unroll
            for (int j = 0; j < 4; ++j) {
                const float p = __expf(sacc[kt][j] - mrow[j]);
                const unsigned short pb = f2bf(p);
                unsigned int pu = ((unsigned int)pb) << 16;
                psum[j] += __builtin_bit_cast(float, pu);
                Plf[w][swz_fb(lg * 4 + j, kt * 16 + lr)] = pb;
            }
        }
        #pragma unroll
        for (int j = 0; j < 4; ++j) {
            float s = psum[j];
            #pragma unroll
            for (int off = 1; off < 16; off <<= 1) s += __shfl_xor(s, off);
            lrow[j] = lrow[j] * alpha[j] + s;
        }
        #pragma unroll
        for (int nn = 0; nn < 4; ++nn) {
            #pragma unroll
            for (int j = 0; j < 4; ++j) oacc[nn][j] *= alpha[j];
        }
        #pragma unroll
        for (int t = 0; t < 2; ++t) {
            s16x8 pf = *(const s16x8*)&Plf[w][swz_fb(lr, t * 32 + lg * 8)];
            #pragma unroll
            for (int nn = 0; nn < 4; ++nn) {
                s16x8 vf = *(const s16x8*)&Vtf[swz_fb(nn * 16 + lr, t * 32 + lg * 8)];
                oacc[nn] = __builtin_amdgcn_mfma_f32_16x16x32_bf16(
                        __builtin_bit_cast(bf16x8, pf),
                        __builtin_bit_cast(bf16x8, vf), oacc[nn], 0, 0, 0);
            }
        }
    }
    #pragma unroll
    for (int j = 0; j < 4; ++j) {
        const float inv = 1.0f / lrow[j];
        #pragma unroll
        for (int nn = 0; nn < 4; ++nn)
            Oh[(size_t)(q0 + lg * 4 + j) * DH + nn * 16 + lr] = oacc[nn][j] * inv;
    }
}

extern "C" void kernel_launch(void* const* d_in, const int* in_sizes, int n_in,
                              void* d_out, int out_size, void* d_ws, size_t ws_size,
                              hipStream_t stream) {
    const float* Q = (const float*)d_in[0];
    const float* K = (const float*)d_in[1];
    const float* V = (const float*)d_in[2];
    float* O = (float*)d_out;

    const size_t elems    = (size_t)NH * S_LEN * DH;   // 4.19M
    const size_t bf_bytes = elems * 2;                 // 8MB per tensor

    unsigned short* Kf = (unsigned short*)d_ws;
    unsigned short* Vf = Kf + elems;

    if (ws_size >= 2 * bf_bytes) {
        prepass_kv<<<NH * 32, 256, 0, stream>>>(K, V, Kf, Vf);
        sdpa_fused<<<NH * 16, 512, 0, stream>>>(Q, Kf, Vf, O);
    } else {
        sdpa_fwd_fb<<<NH * (S_LEN / 64), 256, 0, stream>>>(Q, K, V, O);
    }
}

// Round 12
// 55.949 us; speedup vs baseline: 1.4638x; 1.0437x over previous
//
#include <hip/hip_runtime.h>
#include <cstdint>
#include <cstddef>

typedef __bf16 bf16x8 __attribute__((ext_vector_type(8)));
typedef float f32x4 __attribute__((ext_vector_type(4)));
typedef float f32x16 __attribute__((ext_vector_type(16)));
typedef short s16x8 __attribute__((ext_vector_type(8)));
typedef unsigned short u16x4 __attribute__((ext_vector_type(4)));
typedef unsigned short u16x8 __attribute__((ext_vector_type(8)));
typedef int i32x4 __attribute__((ext_vector_type(4)));

#define S_LEN 2048
#define DH    64
#define BK    64
#define NTILE (S_LEN / BK)
#define NH    32

#if __has_builtin(__builtin_amdgcn_exp2f)
#define EXPF(x) __builtin_amdgcn_exp2f(x)
#define QSCALE 0.18033688011112043f   /* 0.125 * log2(e) */
#else
#define EXPF(x) __expf(x)
#define QSCALE 0.125f
#endif

typedef const __attribute__((address_space(1))) void* gas_ptr;
typedef __attribute__((address_space(3))) void* las_ptr;

static __device__ __forceinline__ unsigned short f2bf(float x) {
    unsigned int u = __builtin_bit_cast(unsigned int, x);
    u += 0x7FFFu + ((u >> 16) & 1u);   // RNE
    return (unsigned short)(u >> 16);
}

static __device__ __forceinline__ unsigned cvtpk(float lo, float hi) {
    unsigned r;
    asm("v_cvt_pk_bf16_f32 %0, %1, %2" : "=v"(r) : "v"(lo), "v"(hi));
    return r;
}

// v_permlane32_swap direction (b): upper half of x <-> lower half of y.
static __device__ __forceinline__ void swap32(int& x, int& y, int hi) {
#if __has_builtin(__builtin_amdgcn_permlane32_swap)
    (void)hi;
    auto r = __builtin_amdgcn_permlane32_swap(x, y, false, false);
    x = r[0]; y = r[1];
#else
    int px = __shfl_xor(x, 32), py = __shfl_xor(y, 32);
    int nx = hi ? py : x;
    int ny = hi ? y  : px;
    x = nx; y = ny;
#endif
}

static __device__ __forceinline__ bf16x8 mkfrag(int lo0, int lo1, int up0, int up1, int hi) {
    swap32(lo0, up0, hi);
    swap32(lo1, up1, hi);
    i32x4 f = {lo0, lo1, up0, up1};
    return __builtin_bit_cast(bf16x8, f);
}

// =====================================================================
// Pre-pass (K/V only): FRAGMENT-ORDERED bf16 chunks (round-8-proven).
//   Kf chunk id: (t*8 + dsub*2 + half)*64 + ln
//   Vf chunk id: (t*8 + ks*2   + half)*64 + ln   (V transposed)
// =====================================================================
__global__ __launch_bounds__(256) void prepass_kv(
        const float* __restrict__ K, const float* __restrict__ V,
        unsigned short* __restrict__ Kf, unsigned short* __restrict__ Vf)
{
    __shared__ float Tl[64][68];
    const int tid = threadIdx.x;
    const int head = blockIdx.x >> 5;
    const int tile = blockIdx.x & 31;

    const size_t hoff = (size_t)head * S_LEN * DH;
    const size_t soff = hoff + (size_t)tile * 64 * DH;

    // ---------- K ----------
    #pragma unroll
    for (int p = 0; p < 4; ++p) {
        const int idx = p * 256 + tid;
        const int row = idx >> 4, c4 = idx & 15;
        *(float4*)&Tl[row][c4 * 4] = *(const float4*)(K + soff + (size_t)row * DH + c4 * 4);
    }
    __syncthreads();
    #pragma unroll
    for (int p = 0; p < 2; ++p) {
        const int cid = p * 256 + tid;
        const int sub = cid >> 6;
        const int ln  = cid & 63;
        const int dsub = sub >> 1, half = sub & 1;
        const int row  = half * 32 + (ln & 31);
        const int d0   = dsub * 16 + (ln >> 5) * 8;
        u16x8 o;
        #pragma unroll
        for (int e = 0; e < 8; ++e) o[e] = f2bf(Tl[row][d0 + e]);
        *(u16x8*)&Kf[hoff + (((size_t)tile * 8 + sub) * 64 + ln) * 8] = o;
    }
    __syncthreads();

    // ---------- V (transposed into fragments) ----------
    #pragma unroll
    for (int p = 0; p < 4; ++p) {
        const int idx = p * 256 + tid;
        const int row = idx >> 4, c4 = idx & 15;
        *(float4*)&Tl[row][c4 * 4] = *(const float4*)(V + soff + (size_t)row * DH + c4 * 4);
    }
    __syncthreads();
    #pragma unroll
    for (int p = 0; p < 2; ++p) {
        const int cid = p * 256 + tid;
        const int sub = cid >> 6;
        const int ln  = cid & 63;
        const int ks = sub >> 1, half = sub & 1;
        const int k0 = ks * 16 + (ln >> 5) * 8;
        const int d  = half * 32 + (ln & 31);
        u16x8 o;
        #pragma unroll
        for (int e = 0; e < 8; ++e) o[e] = f2bf(Tl[k0 + e][d]);
        *(u16x8*)&Vf[hoff + (((size_t)tile * 8 + sub) * 64 + ln) * 8] = o;
    }
}

// =====================================================================
// Main: fused split-K (round-9 body) with T4 counted-vmcnt sync:
// per body {vmcnt(2); bar; QK^T; issue K(t+1); softmax; vmcnt(2); bar;
// PV; issue V(t+1)} — the DMA queue is never drained to 0 in the loop.
// 8 waves = 2 groups x 4; group g = key-half g over the same 128 q-rows.
// =====================================================================
__global__ __launch_bounds__(512, 4) void sdpa_fused(
        const float* __restrict__ Qg, const unsigned short* __restrict__ Kf,
        const unsigned short* __restrict__ Vf, float* __restrict__ O)
{
    // 64KB: K tiles [grp][buf] at grp*8192+buf*4096 (ushort idx), V at
    // 16384 + grp*8192 + buf*4096. Epilogue reuses as float[] (34.8KB).
    __shared__ __attribute__((aligned(16))) unsigned short SH[32768];

    const int tid = threadIdx.x;
    const int w8  = tid >> 6;        // 0..7
    const int grp = w8 >> 2;         // key-half
    const int w   = w8 & 3;          // wave within group
    const int ln  = tid & 63;
    const int r31 = ln & 31;
    const int hi  = ln >> 5;

    // XCD swizzle (bijective: 512 % 8 == 0)
    const int b2 = (blockIdx.x & 7) * 64 + (blockIdx.x >> 3);
    const int n  = b2 >> 4;
    const int qt = b2 & 15;
    const int q0 = qt * 128 + w * 32;

    const size_t hoff = (size_t)n * S_LEN * DH;
    const unsigned short* __restrict__ Kh = Kf + hoff;
    const unsigned short* __restrict__ Vh = Vf + hoff;

    const int kbase = grp * 8192;            // ushort index of this group's K
    const int vbase = 16384 + grp * 8192;    // this group's V

    // Q fragments: fp32 direct load + scale + bf16.
    s16x8 qf[4];
    {
        const float* Qr = Qg + hoff + (size_t)(q0 + r31) * DH;
        #pragma unroll
        for (int dsub = 0; dsub < 4; ++dsub) {
            const float* s = Qr + dsub * 16 + hi * 8;
            float4 a0 = *(const float4*)s, a1 = *(const float4*)(s + 4);
            s16x8 v;
            v[0] = (short)f2bf(a0.x * QSCALE); v[1] = (short)f2bf(a0.y * QSCALE);
            v[2] = (short)f2bf(a0.z * QSCALE); v[3] = (short)f2bf(a0.w * QSCALE);
            v[4] = (short)f2bf(a1.x * QSCALE); v[5] = (short)f2bf(a1.y * QSCALE);
            v[6] = (short)f2bf(a1.z * QSCALE); v[7] = (short)f2bf(a1.w * QSCALE);
            qf[dsub] = v;
        }
    }

    float l = 0.f;
    f32x16 oacc0 = {}, oacc1 = {};

    // per wave: 2 K-chunk loads or 2 V-chunk loads per tile
    auto stage_K = [&](int buf, int t) {
        #pragma unroll
        for (int pass = 0; pass < 2; ++pass) {
            const int c = pass * 256 + w * 64;
            const unsigned short* gk = Kh + ((size_t)t * 512 + c + ln) * 8;
            __builtin_amdgcn_global_load_lds((gas_ptr)gk,
                    (las_ptr)&SH[kbase + buf * 4096 + c * 8], 16, 0, 0);
        }
    };
    auto stage_V = [&](int buf, int t) {
        #pragma unroll
        for (int pass = 0; pass < 2; ++pass) {
            const int c = pass * 256 + w * 64;
            const unsigned short* gv = Vh + ((size_t)t * 512 + c + ln) * 8;
            __builtin_amdgcn_global_load_lds((gas_ptr)gv,
                    (las_ptr)&SH[vbase + buf * 4096 + c * 8], 16, 0, 0);
        }
    };

    const int t0  = grp * (NTILE / 2);   // this group's 16 tiles
    const int NT2 = NTILE / 2;           // 16

    stage_K(0, t0);                      // 2 loads
    stage_V(0, t0);                      // 2 loads  (4 outstanding)

    // body: see header comment. `last` is a literal at every call site ->
    // the waitcnt/issue branches fold at compile time.
    auto body = [&](int it, int cur, bool last) {
        // ---- own K(t) loads done (V(t) may still be in flight), then bar
        asm volatile("s_waitcnt vmcnt(2)" ::: "memory");
        __builtin_amdgcn_s_barrier();

        // ---- S^T = K Q^T
        f32x16 s0 = {}, s1 = {};
        __builtin_amdgcn_s_setprio(1);
        #pragma unroll
        for (int dsub = 0; dsub < 4; ++dsub) {
            s16x8 kf0 = *(const s16x8*)&SH[kbase + cur * 4096 + ((dsub * 2 + 0) * 64 + ln) * 8];
            s16x8 kf1 = *(const s16x8*)&SH[kbase + cur * 4096 + ((dsub * 2 + 1) * 64 + ln) * 8];
            s0 = __builtin_amdgcn_mfma_f32_32x32x16_bf16(
                    __builtin_bit_cast(bf16x8, kf0),
                    __builtin_bit_cast(bf16x8, qf[dsub]), s0, 0, 0, 0);
            s1 = __builtin_amdgcn_mfma_f32_32x32x16_bf16(
                    __builtin_bit_cast(bf16x8, kf1),
                    __builtin_bit_cast(bf16x8, qf[dsub]), s1, 0, 0, 0);
        }
        __builtin_amdgcn_s_setprio(0);

        // ---- prefetch next K tile (into cur^1; safe: all waves passed the
        //      barrier above, so all finished last body's QK^T reads of it)
        if (!last) stage_K(cur ^ 1, t0 + it + 1);

        // ---- zero-max softmax, in place (overlaps K-DMA + V(t) tail)
        #pragma unroll
        for (int i = 0; i < 16; ++i) {
            s0[i] = EXPF(s0[i]);
            s1[i] = EXPF(s1[i]);
        }
        {
            float a0 = 0.f, a1 = 0.f, a2 = 0.f, a3 = 0.f;
            #pragma unroll
            for (int i = 0; i < 16; i += 4) {
                a0 += s0[i];     a1 += s0[i + 1];
                a2 += s0[i + 2]; a3 += s0[i + 3];
                a0 += s1[i];     a1 += s1[i + 1];
                a2 += s1[i + 2]; a3 += s1[i + 3];
            }
            l += (a0 + a1) + (a2 + a3);
        }

        // ---- P^T -> bf16 B-fragments in-register (T12)
        unsigned wa[8], wb[8];
        #pragma unroll
        for (int i = 0; i < 8; ++i) {
            wa[i] = cvtpk(s0[2 * i], s0[2 * i + 1]);
            wb[i] = cvtpk(s1[2 * i], s1[2 * i + 1]);
        }
        bf16x8 pf[4];
        pf[0] = mkfrag(wa[0], wa[1], wa[2], wa[3], hi);
        pf[1] = mkfrag(wa[4], wa[5], wa[6], wa[7], hi);
        pf[2] = mkfrag(wb[0], wb[1], wb[2], wb[3], hi);
        pf[3] = mkfrag(wb[4], wb[5], wb[6], wb[7], hi);

        // ---- own V(t) loads done (K(t+1) still in flight), then bar
        if (last) asm volatile("s_waitcnt vmcnt(0)" ::: "memory");
        else      asm volatile("s_waitcnt vmcnt(2)" ::: "memory");
        __builtin_amdgcn_s_barrier();

        // ---- O^T += V^T P^T
        __builtin_amdgcn_s_setprio(1);
        #pragma unroll
        for (int ks = 0; ks < 4; ++ks) {
            s16x8 vf0 = *(const s16x8*)&SH[vbase + cur * 4096 + ((ks * 2 + 0) * 64 + ln) * 8];
            s16x8 vf1 = *(const s16x8*)&SH[vbase + cur * 4096 + ((ks * 2 + 1) * 64 + ln) * 8];
            oacc0 = __builtin_amdgcn_mfma_f32_32x32x16_bf16(
                    __builtin_bit_cast(bf16x8, vf0), pf[ks], oacc0, 0, 0, 0);
            oacc1 = __builtin_amdgcn_mfma_f32_32x32x16_bf16(
                    __builtin_bit_cast(bf16x8, vf1), pf[ks], oacc1, 0, 0, 0);
        }
        __builtin_amdgcn_s_setprio(0);

        // ---- prefetch next V tile (safe: all waves passed the barrier
        //      above, so all finished last body's PV reads of cur^1)
        if (!last) stage_V(cur ^ 1, t0 + it + 1);
    };

    for (int it = 0; it < NT2 - 2; it += 2) {
        body(it, 0, false);
        body(it + 1, 1, false);
    }
    body(NT2 - 2, 0, false);
    body(NT2 - 1, 1, true);

    // ---- fused combine: group 1 -> LDS, group 0 adds + normalizes + stores
    const float lt = l + __shfl_xor(l, 32);   // this group's full denominator

    __syncthreads();                           // full drain before LDS reuse
    float* xch = (float*)SH;
    if (grp == 1) {
        float* dst = xch + ((size_t)(w * 64 + ln)) * 34;
        #pragma unroll
        for (int i = 0; i < 16; ++i) {
            dst[i]      = oacc0[i];
            dst[16 + i] = oacc1[i];
        }
        dst[32] = lt;
    }
    __syncthreads();
    if (grp == 0) {
        const float* src = xch + ((size_t)(w * 64 + ln)) * 34;
        const float inv = 1.0f / (lt + src[32]);
        float* Orow = O + hoff + (size_t)(q0 + r31) * DH;
        #pragma unroll
        for (int g = 0; g < 4; ++g) {
            float4 o0 = { (oacc0[4*g]   + src[4*g])     * inv,
                          (oacc0[4*g+1] + src[4*g+1])   * inv,
                          (oacc0[4*g+2] + src[4*g+2])   * inv,
                          (oacc0[4*g+3] + src[4*g+3])   * inv };
            *(float4*)&Orow[g * 8 + hi * 4] = o0;
            float4 o1 = { (oacc1[4*g]   + src[16+4*g])   * inv,
                          (oacc1[4*g+1] + src[16+4*g+1]) * inv,
                          (oacc1[4*g+2] + src[16+4*g+2]) * inv,
                          (oacc1[4*g+3] + src[16+4*g+3]) * inv };
            *(float4*)&Orow[32 + g * 8 + hi * 4] = o1;
        }
    }
}

// ---------------- fallback (fp32 in, self-staging, round-1 proven) ------
static __device__ __forceinline__ int swz_fb(int row, int col) {
    return row * 64 + (col ^ ((row & 7) << 3));
}

__global__ __launch_bounds__(256) void sdpa_fwd_fb(
        const float* __restrict__ Q, const float* __restrict__ K,
        const float* __restrict__ V, float* __restrict__ O)
{
    __shared__ __attribute__((aligned(16))) unsigned short Klf[BK * DH];
    __shared__ __attribute__((aligned(16))) unsigned short Vtf[DH * BK];
    __shared__ __attribute__((aligned(16))) unsigned short Plf[4][16 * BK];

    const int tid = threadIdx.x;
    const int w = tid >> 6, ln = tid & 63, lg = ln >> 4, lr = ln & 15;
    const int n = blockIdx.x >> 5, qt = blockIdx.x & 31;
    const int q0 = qt * 64 + w * 16;
    const size_t hoff = (size_t)n * S_LEN * DH;
    const float *Qh = Q + hoff, *Kh = K + hoff, *Vh = V + hoff;
    float* Oh = O + hoff;

    s16x8 qf[2];
    #pragma unroll
    for (int t = 0; t < 2; ++t) {
        const float* src = Qh + (size_t)(q0 + lr) * DH + t * 32 + lg * 8;
        float4 a = *(const float4*)(src);
        float4 b = *(const float4*)(src + 4);
        s16x8 v;
        v[0] = (short)f2bf(a.x * 0.125f); v[1] = (short)f2bf(a.y * 0.125f);
        v[2] = (short)f2bf(a.z * 0.125f); v[3] = (short)f2bf(a.w * 0.125f);
        v[4] = (short)f2bf(b.x * 0.125f); v[5] = (short)f2bf(b.y * 0.125f);
        v[6] = (short)f2bf(b.z * 0.125f); v[7] = (short)f2bf(b.w * 0.125f);
        qf[t] = v;
    }
    float mrow[4] = {-INFINITY, -INFINITY, -INFINITY, -INFINITY};
    float lrow[4] = {0.f, 0.f, 0.f, 0.f};
    f32x4 oacc[4];
    #pragma unroll
    for (int nn = 0; nn < 4; ++nn) oacc[nn] = (f32x4){0.f, 0.f, 0.f, 0.f};

    for (int it = 0; it < NTILE; ++it) {
        const int k0 = it * BK;
        __syncthreads();
        #pragma unroll
        for (int r4 = 0; r4 < 4; ++r4) {
            const int lin = tid + 256 * r4;
            const int row = lin >> 4, c4 = lin & 15;
            float4 kv = *(const float4*)(Kh + (size_t)(k0 + row) * DH + c4 * 4);
            u16x4 kb;
            kb[0] = f2bf(kv.x); kb[1] = f2bf(kv.y); kb[2] = f2bf(kv.z); kb[3] = f2bf(kv.w);
            *(u16x4*)&Klf[swz_fb(row, c4 * 4)] = kb;
            float4 vv = *(const float4*)(Vh + (size_t)(k0 + row) * DH + c4 * 4);
            const float vals[4] = {vv.x, vv.y, vv.z, vv.w};
            #pragma unroll
            for (int ii = 0; ii < 4; ++ii) Vtf[swz_fb(c4 * 4 + ii, row)] = f2bf(vals[ii]);
        }
        __syncthreads();
        f32x4 sacc[4];
        #pragma unroll
        for (int kt = 0; kt < 4; ++kt) {
            f32x4 acc = (f32x4){0.f, 0.f, 0.f, 0.f};
            #pragma unroll
            for (int t = 0; t < 2; ++t) {
                s16x8 kf = *(const s16x8*)&Klf[swz_fb(kt * 16 + lr, t * 32 + lg * 8)];
                acc = __builtin_amdgcn_mfma_f32_16x16x32_bf16(
                        __builtin_bit_cast(bf16x8, qf[t]),
                        __builtin_bit_cast(bf16x8, kf), acc, 0, 0, 0);
            }
            sacc[kt] = acc;
        }
        float alpha[4];
        #pragma unroll
        for (int j = 0; j < 4; ++j) {
            float v = fmaxf(fmaxf(sacc[0][j], sacc[1][j]), fmaxf(sacc[2][j], sacc[3][j]));
            #pragma unroll
            for (int off = 1; off < 16; off <<= 1) v = fmaxf(v, __shfl_xor(v, off));
            const float mn = fmaxf(mrow[j], v);
            alpha[j] = __expf(mrow[j] - mn);
            mrow[j] = mn;
        }
        float psum[4] = {0.f, 0.f, 0.f, 0.f};
        #pragma unroll
        for (int kt = 0; kt < 4; ++kt) {
            #pragma unroll
            for (int j = 0; j < 4; ++j) {
                const float p = __expf(sacc[kt][j] - mrow[j]);
                const unsigned short pb = f2bf(p);
                unsigned int pu = ((unsigned int)pb) << 16;
                psum[j] += __builtin_bit_cast(float, pu);
                Plf[w][swz_fb(lg * 4 + j, kt * 16 + lr)] = pb;
            }
        }
        #pragma unroll
        for (int j = 0; j < 4; ++j) {
            float s = psum[j];
            #pragma unroll
            for (int off = 1; off < 16; off <<= 1) s += __shfl_xor(s, off);
            lrow[j] = lrow[j] * alpha[j] + s;
        }
        #pragma unroll
        for (int nn = 0; nn < 4; ++nn) {
            #pragma unroll
            for (int j = 0; j < 4; ++j) oacc[nn][j] *= alpha[j];
        }
        #pragma unroll
        for (int t = 0; t < 2; ++t) {
            s16x8 pf = *(const s16x8*)&Plf[w][swz_fb(lr, t * 32 + lg * 8)];
            #pragma unroll
            for (int nn = 0; nn < 4; ++nn) {
                s16x8 vf = *(const s16x8*)&Vtf[swz_fb(nn * 16 + lr, t * 32 + lg * 8)];
                oacc[nn] = __builtin_amdgcn_mfma_f32_16x16x32_bf16(
                        __builtin_bit_cast(bf16x8, pf),
                        __builtin_bit_cast(bf16x8, vf), oacc[nn], 0, 0, 0);
            }
        }
    }
    #pragma unroll
    for (int j = 0; j < 4; ++j) {
        const float inv = 1.0f / lrow[j];
        #pragma unroll
        for (int nn = 0; nn < 4; ++nn)
            Oh[(size_t)(q0 + lg * 4 + j) * DH + nn * 16 + lr] = oacc[nn][j] * inv;
    }
}

extern "C" void kernel_launch(void* const* d_in, const int* in_sizes, int n_in,
                              void* d_out, int out_size, void* d_ws, size_t ws_size,
                              hipStream_t stream) {
    const float* Q = (const float*)d_in[0];
    const float* K = (const float*)d_in[1];
    const float* V = (const float*)d_in[2];
    float* O = (float*)d_out;

    const size_t elems    = (size_t)NH * S_LEN * DH;   // 4.19M
    const size_t bf_bytes = elems * 2;                 // 8MB per tensor

    unsigned short* Kf = (unsigned short*)d_ws;
    unsigned short* Vf = Kf + elems;

    if (ws_size >= 2 * bf_bytes) {
        prepass_kv<<<NH * 32, 256, 0, stream>>>(K, V, Kf, Vf);
        sdpa_fused<<<NH * 16, 512, 0, stream>>>(Q, Kf, Vf, O);
    } else {
        sdpa_fwd_fb<<<NH * (S_LEN / 64), 256, 0, stream>>>(Q, K, V, O);
    }
}